// Round 1
// baseline (308.726 us; speedup 1.0000x reference)
//
#include <hip/hip_runtime.h>
#include <hip/hip_bf16.h>
#include <cstdint>

// B=512, D=256, H=512. out: [512,512] fp32.
// ws layout: Ai [512*512] f32 | Aj [512*512] f32 (b1 folded) | W2s [512*512] bf16 (swizzled)

#define NB 512
#define ND 256
#define NH 512

typedef float f32x16 __attribute__((ext_vector_type(16)));
typedef __bf16 bf16x8 __attribute__((ext_vector_type(8)));
typedef unsigned int u32;
typedef unsigned short u16;

__device__ __forceinline__ float tanh_fast(float x) {
  // tanh(x) = 1 - 2/(exp2(x*2*log2e)+1); saturates correctly at +/-inf.
#if __has_builtin(__builtin_amdgcn_exp2f)
  float e = __builtin_amdgcn_exp2f(x * 2.885390081777927f);
#else
  float e = exp2f(x * 2.885390081777927f);
#endif
#if __has_builtin(__builtin_amdgcn_rcpf)
  return 1.0f - 2.0f * __builtin_amdgcn_rcpf(e + 1.0f);
#else
  return 1.0f - 2.0f / (e + 1.0f);
#endif
}

__device__ __forceinline__ u16 f2bf(float f) {  // RNE f32->bf16
  u32 u = __builtin_bit_cast(u32, f);
  u += 0x7FFFu + ((u >> 16) & 1u);
  return (u16)(u >> 16);
}

// ---------------- prep 1: Ai = h @ W1[:256]; Aj = h @ W1[256:] + b1 ----------------
// grid 128 x 256 threads; each block does 4 rows, thread t does cols {t, t+256}.
__global__ __launch_bounds__(256) void prep_gemm(const float* __restrict__ h,
                                                 const float* __restrict__ W1,
                                                 const float* __restrict__ b1,
                                                 float* __restrict__ Ai,
                                                 float* __restrict__ Aj) {
  __shared__ float hs[4][ND];
  const int t = threadIdx.x;
  const int i0 = blockIdx.x * 4;
  for (int idx = t; idx < 4 * ND; idx += 256) hs[idx >> 8][idx & 255] = h[i0 * ND + idx];
  __syncthreads();
  float ai0[4] = {0, 0, 0, 0}, ai1[4] = {0, 0, 0, 0};
  float aj0[4] = {0, 0, 0, 0}, aj1[4] = {0, 0, 0, 0};
#pragma unroll 4
  for (int d = 0; d < ND; ++d) {
    const float wA0 = W1[d * NH + t];
    const float wA1 = W1[d * NH + t + 256];
    const float wB0 = W1[(d + ND) * NH + t];
    const float wB1 = W1[(d + ND) * NH + t + 256];
#pragma unroll
    for (int r = 0; r < 4; ++r) {
      const float hd = hs[r][d];
      ai0[r] = fmaf(hd, wA0, ai0[r]);
      ai1[r] = fmaf(hd, wA1, ai1[r]);
      aj0[r] = fmaf(hd, wB0, aj0[r]);
      aj1[r] = fmaf(hd, wB1, aj1[r]);
    }
  }
  const float b1a = b1[t], b1b = b1[t + 256];
#pragma unroll
  for (int r = 0; r < 4; ++r) {
    const int i = i0 + r;
    Ai[i * NH + t] = ai0[r];
    Ai[i * NH + t + 256] = ai1[r];
    Aj[i * NH + t] = aj0[r] + b1a;
    Aj[i * NH + t + 256] = aj1[r] + b1b;
  }
}

// ---------------- prep 2: W2 -> bf16, swizzled to MFMA B-frag order ----------------
// W2s element ((kk*16+nt)*2+kh)*512 + lane*8 + j  =  bf16(W2[k][n])
//   with k = kk*32 + kh*16 + (lane>>5)*8 + j,  n = nt*32 + (lane&31)
__global__ __launch_bounds__(256) void prep_w2(const float* __restrict__ W2,
                                               u16* __restrict__ W2s) {
  const int g = blockIdx.x * 256 + threadIdx.x;  // 0..32767, one 8-elem group each
  const int lane = g & 63;
  const int kh = (g >> 6) & 1;
  const int nt = (g >> 7) & 15;
  const int kk = g >> 11;
  const int k = kk * 32 + kh * 16 + ((lane >> 5) << 3);
  const int n = nt * 32 + (lane & 31);
  u32 p[4];
#pragma unroll
  for (int q = 0; q < 4; ++q) {
    const u16 lo = f2bf(W2[(k + 2 * q) * NH + n]);
    const u16 hi = f2bf(W2[(k + 2 * q + 1) * NH + n]);
    p[q] = (u32)lo | ((u32)hi << 16);
  }
  uint4 pw = make_uint4(p[0], p[1], p[2], p[3]);
  *(uint4*)(W2s + (size_t)g * 8) = pw;
}

// ---------------- main: fused pairwise tanh-MLP ----------------
// Block: 256 thr (4 waves). Tile: M=64 pairs (fixed i, 64 consecutive j), N=512, K=512.
// Wave w covers n in [w*128, w*128+128) as 4 tiles of 32; 2 m-tiles of 32. BK=32.
__global__ __launch_bounds__(256, 2) void pair_main(const float* __restrict__ Ai,
                                                    const float* __restrict__ Aj,
                                                    const u16* __restrict__ W2s,
                                                    const float* __restrict__ b2,
                                                    const float* __restrict__ W3,
                                                    const float* __restrict__ b3,
                                                    float* __restrict__ out) {
  __shared__ __align__(16) u16 xs[2 * 2 * 64 * 8];     // 4 KB  [(mt*2+kh)*64+lane][8]
  __shared__ __align__(16) u16 w2t[16 * 2 * 64 * 8];   // 32 KB [(nt*2+kh)*64+lane][8]
  __shared__ float ai_lds[NH];                          // 2 KB
  __shared__ float red[4][64];                          // 1 KB

  const int t = threadIdx.x;
  const int wave = t >> 6;
  const int lane = t & 63;
  const int bx = blockIdx.x;
  const int i = bx >> 3;
  const int j0 = (bx & 7) * 64;

  for (int idx = t; idx < NH; idx += 256) ai_lds[idx] = Ai[i * NH + idx];

  f32x16 acc[2][4];
#pragma unroll
  for (int mt = 0; mt < 2; ++mt)
#pragma unroll
    for (int nt = 0; nt < 4; ++nt)
#pragma unroll
      for (int q = 0; q < 16; ++q) acc[mt][nt][q] = 0.0f;

  // staging mapping: thread t -> row sm = t>>2 (j-local), k-chunk sc = t&3 (8 k's)
  const int sm = t >> 2;
  const int sc = t & 3;
  const float* ajp = Aj + (size_t)(j0 + sm) * NH + sc * 8;
  const int gofs = ((((sm >> 5) * 2 + (sc >> 1)) * 64) + ((sc & 1) << 5) + (sm & 31)) * 8;
  const int aio = sc * 8;

  const u16* w2g = W2s + wave * 4096 + lane * 8;  // + kk*16384 + s*512 per step

  for (int kk = 0; kk < 16; ++kk) {
    __syncthreads();  // previous tile consumed
    // ---- stage X = tanh(Ai[i,:] + Aj[j,:]) as bf16 (one ds_write_b128/thread) ----
    const float* ap = ajp + kk * 32;
    const float4 f0 = *(const float4*)(ap);
    const float4 f1 = *(const float4*)(ap + 4);
    const float* aip = ai_lds + kk * 32 + aio;
    const float4 g0 = *(const float4*)(aip);
    const float4 g1 = *(const float4*)(aip + 4);
    float v[8];
    v[0] = f0.x + g0.x; v[1] = f0.y + g0.y; v[2] = f0.z + g0.z; v[3] = f0.w + g0.w;
    v[4] = f1.x + g1.x; v[5] = f1.y + g1.y; v[6] = f1.z + g1.z; v[7] = f1.w + g1.w;
    u32 p[4];
#pragma unroll
    for (int q = 0; q < 4; ++q) {
      const u16 lo = f2bf(tanh_fast(v[2 * q]));
      const u16 hi = f2bf(tanh_fast(v[2 * q + 1]));
      p[q] = (u32)lo | ((u32)hi << 16);
    }
    uint4 pw = make_uint4(p[0], p[1], p[2], p[3]);
    *(uint4*)(xs + gofs) = pw;
    // ---- stage W2 K-slab (32 KB) via global_load_lds dwordx4 ----
    {
      const u16* gs = w2g + kk * 16384;
      u16* lb = w2t + wave * 4096;
#pragma unroll
      for (int s = 0; s < 8; ++s) {
        __builtin_amdgcn_global_load_lds(
            (const __attribute__((address_space(1))) u32*)(gs + s * 512),
            (__attribute__((address_space(3))) u32*)(lb + s * 512), 16, 0, 0);
      }
    }
    __syncthreads();  // staging visible (vmcnt drained by barrier)
    // ---- MFMA ----
#pragma unroll
    for (int kh = 0; kh < 2; ++kh) {
      const bf16x8 a0 = __builtin_bit_cast(bf16x8, *(const uint4*)(xs + ((0 * 2 + kh) * 64 + lane) * 8));
      const bf16x8 a1 = __builtin_bit_cast(bf16x8, *(const uint4*)(xs + ((1 * 2 + kh) * 64 + lane) * 8));
#pragma unroll
      for (int ntl = 0; ntl < 4; ++ntl) {
        const int nt = wave * 4 + ntl;
        const bf16x8 bb = __builtin_bit_cast(bf16x8, *(const uint4*)(w2t + ((nt * 2 + kh) * 64 + lane) * 8));
        acc[0][ntl] = __builtin_amdgcn_mfma_f32_32x32x16_bf16(a0, bb, acc[0][ntl], 0, 0, 0);
        acc[1][ntl] = __builtin_amdgcn_mfma_f32_32x32x16_bf16(a1, bb, acc[1][ntl], 0, 0, 0);
      }
    }
  }

  // ---- epilogue: z = tanh(acc + b2), partial[m] = sum_n z*W3[n] ----
  float b2v[4], w3v[4];
#pragma unroll
  for (int ntl = 0; ntl < 4; ++ntl) {
    const int n = wave * 128 + ntl * 32 + (lane & 31);
    b2v[ntl] = b2[n];
    w3v[ntl] = W3[n];
  }
#pragma unroll
  for (int mt = 0; mt < 2; ++mt) {
#pragma unroll
    for (int reg = 0; reg < 16; ++reg) {
      float s = 0.0f;
#pragma unroll
      for (int ntl = 0; ntl < 4; ++ntl)
        s += tanh_fast(acc[mt][ntl][reg] + b2v[ntl]) * w3v[ntl];
      // reduce across the 32 columns (lanes within each half)
#pragma unroll
      for (int off = 1; off < 32; off <<= 1) s += __shfl_xor(s, off, 64);
      const int row = (reg & 3) + 8 * (reg >> 2) + 4 * (lane >> 5);
      if ((lane & 31) == reg) red[wave][mt * 32 + row] = s;
    }
  }
  __syncthreads();
  if (t < 64) {
    const float r = red[0][t] + red[1][t] + red[2][t] + red[3][t] + b3[0];
    const int j = j0 + t;
    out[i * NB + j] = (j == i) ? -20.0f : r;
  }
}

extern "C" void kernel_launch(void* const* d_in, const int* in_sizes, int n_in,
                              void* d_out, int out_size, void* d_ws, size_t ws_size,
                              hipStream_t stream) {
  const float* h = (const float*)d_in[0];
  const float* W1 = (const float*)d_in[1];
  const float* b1 = (const float*)d_in[2];
  const float* W2 = (const float*)d_in[3];
  const float* b2 = (const float*)d_in[4];
  const float* W3 = (const float*)d_in[5];
  const float* b3 = (const float*)d_in[6];
  float* out = (float*)d_out;

  float* Ai = (float*)d_ws;
  float* Aj = Ai + NB * NH;
  u16* W2s = (u16*)(Aj + NB * NH);

  prep_gemm<<<128, 256, 0, stream>>>(h, W1, b1, Ai, Aj);
  prep_w2<<<128, 256, 0, stream>>>(W2, W2s);
  pair_main<<<4096, 256, 0, stream>>>(Ai, Aj, W2s, b2, W3, b3, out);
}